// Round 3
// baseline (381.085 us; speedup 1.0000x reference)
//
#include <hip/hip_runtime.h>
#include <math.h>

static constexpr float kSigma = 3.5412f;
static constexpr float kMu    = -9.1232f;
static constexpr int   kT     = 1024;
static constexpr float kTwoPi = 6.28318530717958647692f;

// W[b] = 0.5*X[b] - 0.25*(X[b-1] + X[b+1])  (freq-domain periodic Hann)
__device__ __forceinline__ float wmag(float pmre, float pmim, float pcre, float pcim,
                                      float ppre, float ppim) {
    const float wre = 0.5f * pcre - 0.25f * (pmre + ppre);
    const float wim = 0.5f * pcim - 0.25f * (pmim + ppim);
    return sqrtf(fmaf(wre, wre, wim * wim)) + 1e-7f;
}

__device__ __forceinline__ void accum(float mx, float my,
                                      float& sd2, float& sy2, float& slg) {
    const float d = my - mx;
    sd2 = fmaf(d, d, sd2);
    sy2 = fmaf(my, my, sy2);
    slg += fabsf(__logf(__fdividef(mx, my)));
}

// Goertzel step: s1' = v - s2 + co*s1 ; s2' = s1   (co = 2cos(w))
#define GSTEP(s1, s2, co, v) { const float _t = (v) - s2; s2 = s1; s1 = fmaf(co, s2, _t); }

#define COEF4(BASE) \
    float cb0, sb0, cb1, sb1, cb2, sb2, cb3, sb3; \
    __sincosf((BASE) + STEP * 1.f, &sb0, &cb0); \
    __sincosf((BASE) + STEP * 2.f, &sb1, &cb1); \
    __sincosf((BASE) + STEP * 3.f, &sb2, &cb2); \
    __sincosf((BASE) + STEP * 4.f, &sb3, &cb3); \
    const float co0 = cb0 + cb0, co1 = cb1 + cb1, co2 = cb2 + cb2, co3 = cb3 + cb3;

#define BIN4_DECL \
    float s1x0=0,s2x0=0,s1y0=0,s2y0=0, s1x1=0,s2x1=0,s1y1=0,s2y1=0, \
          s1x2=0,s2x2=0,s1y2=0,s2y2=0, s1x3=0,s2x3=0,s1y3=0,s2y3=0;

#define BIN4_STEP(xv, yv) \
    GSTEP(s1x0, s2x0, co0, xv); GSTEP(s1y0, s2y0, co0, yv); \
    GSTEP(s1x1, s2x1, co1, xv); GSTEP(s1y1, s2y1, co1, yv); \
    GSTEP(s1x2, s2x2, co2, xv); GSTEP(s1y2, s2y2, co2, yv); \
    GSTEP(s1x3, s2x3, co3, xv); GSTEP(s1y3, s2y3, co3, yv);

#define BIN4_EPI \
    const float n0xre = fmaf(s1x0, cb0, -s2x0), n0xim = s1x0 * sb0; \
    const float n0yre = fmaf(s1y0, cb0, -s2y0), n0yim = s1y0 * sb0; \
    const float n1xre = fmaf(s1x1, cb1, -s2x1), n1xim = s1x1 * sb1; \
    const float n1yre = fmaf(s1y1, cb1, -s2y1), n1yim = s1y1 * sb1; \
    const float n2xre = fmaf(s1x2, cb2, -s2x2), n2xim = s1x2 * sb2; \
    const float n2yre = fmaf(s1y2, cb2, -s2y2), n2yim = s1y2 * sb2; \
    const float n3xre = fmaf(s1x3, cb3, -s2x3), n3xim = s1x3 * sb3; \
    const float n3yre = fmaf(s1y3, cb3, -s2y3), n3yim = s1y3 * sb3;

#define KLOOP(...) \
    _Pragma("unroll 16") \
    for (int k = 0; k < NFFT; ++k) { \
        const int jj = sj + k; \
        const int a = jj + (jj >> 4); \
        const float xv = lx[a], yv = ly[a]; \
        __VA_ARGS__ \
        BIN4_STEP(xv, yv) \
    }

#define EMIT(pm, pc, pp) \
    accum(wmag(pm##xre, pm##xim, pc##xre, pc##xim, pp##xre, pp##xim), \
          wmag(pm##yre, pm##yim, pc##yre, pc##yim, pp##yre, pp##yim), sd2, sy2, slg)

#define SHIFT_H \
    h2xre = n2xre; h2xim = n2xim; h2yre = n2yre; h2yim = n2yim; \
    h1xre = n3xre; h1xim = n3xim; h1yre = n3yre; h1yim = n3yim;

// chunk 0: bin 0 (running sum) + bins 1..4 (Goertzel); emits W0..W3, leaves h2=X3,h1=X4
#define CHUNK0 { \
    COEF4(0.f) \
    BIN4_DECL \
    float s0x = 0.f, s0y = 0.f; \
    KLOOP(s0x += xv; s0y += yv;) \
    BIN4_EPI \
    { const float mx = fabsf(0.5f * s0x - 0.5f * n0xre) + 1e-7f; \
      const float my = fabsf(0.5f * s0y - 0.5f * n0yre) + 1e-7f; \
      accum(mx, my, sd2, sy2, slg); } \
    const float z0xre = s0x, z0xim = 0.f, z0yre = s0y, z0yim = 0.f; \
    EMIT(z0, n0, n1); EMIT(n0, n1, n2); EMIT(n1, n2, n3); \
    SHIFT_H }

// generic chunk c >= 1: emits W[4c..4c+3]; invariant h2=X[4c-1], h1=X[4c]
#define CHUNKC(CEXPR) { \
    asm volatile("" ::: "memory"); \
    COEF4(STEP * (float)(4 * (CEXPR))) \
    BIN4_DECL \
    KLOOP() \
    BIN4_EPI \
    EMIT(h2, h1, n0); EMIT(h1, n0, n1); EMIT(n0, n1, n2); EMIT(n1, n2, n3); \
    SHIFT_H }

// W[N/2] from h1=X[N/2], h2=X[N/2-1]
#define FINALBIN { \
    const float wxre = 0.5f * h1xre - 0.5f * h2xre; \
    const float wxim = 0.5f * h1xim; \
    const float wyre = 0.5f * h1yre - 0.5f * h2yre; \
    const float wyim = 0.5f * h1yim; \
    const float mx = sqrtf(fmaf(wxre, wxre, wxim * wxim)) + 1e-7f; \
    const float my = sqrtf(fmaf(wyre, wyre, wyim * wyim)) + 1e-7f; \
    accum(mx, my, sd2, sy2, slg); }

template <int NFFT>
__device__ __forceinline__ void frame_full(const float* __restrict__ lx,
                                           const float* __restrict__ ly, int sj,
                                           float& sd2, float& sy2, float& slg)
{
    constexpr int NCH = NFFT / 8;
    constexpr float STEP = kTwoPi / NFFT;
    float h1xre, h1xim, h2xre, h2xim, h1yre, h1yim, h2yre, h2yim;
    CHUNK0
#pragma unroll 1
    for (int c = 1; c < NCH; ++c) CHUNKC(c)
    FINALBIN
}

// NFFT=64 frame split in two items: part0 = chunks 0..3 (W0..W15),
// part1 = bootstrap X15,X16 then chunks 4..7 + final (W16..W32)
__device__ __forceinline__ void frame64_part(const float* __restrict__ lx,
                                             const float* __restrict__ ly, int sj,
                                             int part, float& sd2, float& sy2, float& slg)
{
    constexpr int NFFT = 64;
    constexpr float STEP = kTwoPi / 64;
    float h1xre, h1xim, h2xre, h2xim, h1yre, h1yim, h2yre, h2yim;
    int c0, c1;
    if (part == 0) {
        CHUNK0
        c0 = 1; c1 = 4;
    } else {
        float s1x0=0,s2x0=0,s1y0=0,s2y0=0, s1x1=0,s2x1=0,s1y1=0,s2y1=0;
        float cbA, sbA, cbB, sbB;
        __sincosf(STEP * 15.f, &sbA, &cbA);
        __sincosf(STEP * 16.f, &sbB, &cbB);
        const float coA = cbA + cbA, coB = cbB + cbB;
#pragma unroll 16
        for (int k = 0; k < NFFT; ++k) {
            const int jj = sj + k;
            const int a = jj + (jj >> 4);
            const float xv = lx[a], yv = ly[a];
            GSTEP(s1x0, s2x0, coA, xv); GSTEP(s1y0, s2y0, coA, yv);
            GSTEP(s1x1, s2x1, coB, xv); GSTEP(s1y1, s2y1, coB, yv);
        }
        h2xre = fmaf(s1x0, cbA, -s2x0); h2xim = s1x0 * sbA;
        h2yre = fmaf(s1y0, cbA, -s2y0); h2yim = s1y0 * sbA;
        h1xre = fmaf(s1x1, cbB, -s2x1); h1xim = s1x1 * sbB;
        h1yre = fmaf(s1y1, cbB, -s2y1); h1yim = s1y1 * sbB;
        c0 = 4; c1 = 8;
    }
#pragma unroll 1
    for (int c = c0; c < c1; ++c) CHUNKC(c)
    if (part) FINALBIN
}

// cost-prefix schedule: item i of resolution (S,C) belongs to thread whose
// window [A,B) contains S + i*C
#define SCHED(S, CNT, C, lo, hi) \
    int lo = (A > (S)) ? (A - (S) + (C) - 1) / (C) : 0; \
    int hi = (B > (S)) ? ((B - (S) + (C) - 1) / (C)) : 0; \
    hi = min(hi, (CNT)); lo = min(lo, hi);

__global__ __launch_bounds__(256)
void fused_stft_kernel(const float* __restrict__ xg, const float* __restrict__ yg,
                       float* __restrict__ acc)
{
    constexpr int R = 4;                       // rows per block
    constexpr int PLen = 1088;                 // padded row: j in [0,1088), i = j-32
    constexpr int RSTRIDE = PLen + PLen / 16 + 1;   // 1157 (pad every 16 floats)

    __shared__ float lds[2][R][RSTRIDE];
    __shared__ float red[12][4];

    const int tid  = threadIdx.x;
    const int row0 = blockIdx.x * R;

    // ---- stage central 1024 floats per row/signal as float4
    for (int task = tid; task < 2048; task += 256) {
        const int sig = task >> 10, rr = (task >> 8) & 3, q = task & 255;
        const float* __restrict__ src = sig ? yg : xg;
        const float4 v = reinterpret_cast<const float4*>(src)[(row0 + rr) * 256 + q];
        const int j = 32 + 4 * q;
        const int a = j + (j >> 4);            // 4 contiguous (no pad boundary inside)
        float* __restrict__ dst = &lds[sig][rr][a];
        dst[0] = __expf(fmaf(v.x, kSigma, kMu));
        dst[1] = __expf(fmaf(v.y, kSigma, kMu));
        dst[2] = __expf(fmaf(v.z, kSigma, kMu));
        dst[3] = __expf(fmaf(v.w, kSigma, kMu));
    }
    // ---- stage reflect pads (32 each side per row/signal)
    for (int task = tid; task < 512; task += 256) {
        const int sig = task >> 8, rr = (task >> 6) & 3, p = task & 63;
        const int j = (p < 32) ? p : (1024 + p);       // [0,32) or [1056,1088)
        const int i = (j < 32) ? (32 - j) : (2078 - j);
        const float* __restrict__ src = sig ? yg : xg;
        const int a = j + (j >> 4);
        lds[sig][rr][a] = __expf(fmaf(src[(row0 + rr) * kT + i], kSigma, kMu));
    }
    __syncthreads();

    // ---- balanced compute: cost units {n64half:24, n32:12, n16:3, n8:1}
    // totals/block: 520*24 + 516*12 + 1028*3 + 2052*1 = 23808 = 256*93
    const int A = 93 * tid, B = A + 93;

    float sdA=0, syA=0, slA=0;   // n8
    float sdB=0, syB=0, slB=0;   // n16
    float sdC=0, syC=0, slC=0;   // n32
    float sdD=0, syD=0, slD=0;   // n64

    { // n64 half-frames: S=0
        SCHED(0, 520, 24, lo, hi)
#pragma unroll 1
        for (int it = lo; it < hi; ++it) {
            const int f = it >> 1, part = it & 1;
            const int rr = f / 65, t = f - rr * 65;
            frame64_part(&lds[0][rr][0], &lds[1][rr][0], 16 * t, part, sdD, syD, slD);
        }
    }
    { // n32: S=12480
        SCHED(12480, 516, 12, lo, hi)
#pragma unroll 1
        for (int it = lo; it < hi; ++it) {
            const int rr = it / 129, t = it - rr * 129;
            frame_full<32>(&lds[0][rr][0], &lds[1][rr][0], 8 * t + 16, sdC, syC, slC);
        }
    }
    { // n16: S=18672
        SCHED(18672, 1028, 3, lo, hi)
#pragma unroll 1
        for (int it = lo; it < hi; ++it) {
            const int rr = it / 257, t = it - rr * 257;
            frame_full<16>(&lds[0][rr][0], &lds[1][rr][0], 4 * t + 24, sdB, syB, slB);
        }
    }
    { // n8: S=21756
        SCHED(21756, 2052, 1, lo, hi)
#pragma unroll 1
        for (int it = lo; it < hi; ++it) {
            const int rr = it / 513, t = it - rr * 513;
            frame_full<8>(&lds[0][rr][0], &lds[1][rr][0], 2 * t + 28, sdA, syA, slA);
        }
    }

    // ---- reduce 12 partials: wave shuffle -> LDS -> atomics
    float v0=sdA, v1=syA, v2=slA, v3=sdB, v4=syB, v5=slB,
          v6=sdC, v7=syC, v8=slC, v9=sdD, v10=syD, v11=slD;
#pragma unroll
    for (int off = 32; off > 0; off >>= 1) {
        v0 += __shfl_down(v0, off);  v1 += __shfl_down(v1, off);
        v2 += __shfl_down(v2, off);  v3 += __shfl_down(v3, off);
        v4 += __shfl_down(v4, off);  v5 += __shfl_down(v5, off);
        v6 += __shfl_down(v6, off);  v7 += __shfl_down(v7, off);
        v8 += __shfl_down(v8, off);  v9 += __shfl_down(v9, off);
        v10 += __shfl_down(v10, off); v11 += __shfl_down(v11, off);
    }
    const int wid = tid >> 6, lane = tid & 63;
    if (lane == 0) {
        red[0][wid]=v0;  red[1][wid]=v1;  red[2][wid]=v2;  red[3][wid]=v3;
        red[4][wid]=v4;  red[5][wid]=v5;  red[6][wid]=v6;  red[7][wid]=v7;
        red[8][wid]=v8;  red[9][wid]=v9;  red[10][wid]=v10; red[11][wid]=v11;
    }
    __syncthreads();
    if (tid < 12) {
        const float s = red[tid][0] + red[tid][1] + red[tid][2] + red[tid][3];
        atomicAdd(&acc[tid * 64], s);
    }
}

__global__ void finalize_kernel(const float* __restrict__ acc,
                                float* __restrict__ out)
{
    if (threadIdx.x == 0 && blockIdx.x == 0) {
        // acc layout: [r8: sd,sy,sl][r16: ...][r32][r64], stride 64 floats
        const float nel[4] = {10506240.f, 9474048.f, 8982528.f, 8785920.f};
        float sc = 0.f, mg = 0.f;
#pragma unroll
        for (int r = 0; r < 4; ++r) {
            const float a0 = acc[(r * 3 + 0) * 64];
            const float a1 = acc[(r * 3 + 1) * 64];
            const float a2 = acc[(r * 3 + 2) * 64];
            sc += sqrtf(a0) / (sqrtf(a1) + 1e-8f);
            mg += a2 / nel[r];
        }
        out[0] = sc * 0.25f;
        out[1] = mg * 0.25f;
    }
}

extern "C" void kernel_launch(void* const* d_in, const int* in_sizes, int n_in,
                              void* d_out, int out_size, void* d_ws, size_t ws_size,
                              hipStream_t stream)
{
    const float* x = (const float*)d_in[0];
    const float* y = (const float*)d_in[1];
    float* out = (float*)d_out;
    float* acc = (float*)d_ws;   // 12 accumulators at 64-float stride

    hipMemsetAsync(acc, 0, 12 * 64 * sizeof(float), stream);
    fused_stft_kernel<<<1024, 256, 0, stream>>>(x, y, acc);
    finalize_kernel<<<1, 64, 0, stream>>>(acc, out);
}

// Round 4
// 141.514 us; speedup vs baseline: 2.6929x; 2.6929x over previous
//
#include <hip/hip_runtime.h>
#include <math.h>

static constexpr float kSigma = 3.5412f;
static constexpr float kMu    = -9.1232f;

// ---------- compile-time twiddles: cos / -sin of 2*pi*k/n (constexpr Taylor) ----------
constexpr double kPId = 3.14159265358979323846264338327950288;

constexpr double tp_sin(double r) {
    const double r2 = r * r;
    double t = r, s = r;
    t *= -r2 / (2.0 * 3.0);   s += t;
    t *= -r2 / (4.0 * 5.0);   s += t;
    t *= -r2 / (6.0 * 7.0);   s += t;
    t *= -r2 / (8.0 * 9.0);   s += t;
    t *= -r2 / (10.0 * 11.0); s += t;
    t *= -r2 / (12.0 * 13.0); s += t;
    return s;
}
constexpr double tp_cos(double r) {
    const double r2 = r * r;
    double t = 1.0, c = 1.0;
    t *= -r2 / (1.0 * 2.0);   c += t;
    t *= -r2 / (3.0 * 4.0);   c += t;
    t *= -r2 / (5.0 * 6.0);   c += t;
    t *= -r2 / (7.0 * 8.0);   c += t;
    t *= -r2 / (9.0 * 10.0);  c += t;
    t *= -r2 / (11.0 * 12.0); c += t;
    return c;
}
// cos(2*pi*k/n) via exact integer quadrant reduction
constexpr float ctw_c(int k, int n) {
    const int kk = ((k % n) + n) % n;
    const int q = (4 * kk) / n;
    const int num = 4 * kk - q * n;
    const double r = (2.0 * kPId * num) / (4.0 * n);
    const double cr = tp_cos(r), sr = tp_sin(r);
    return (float)(q == 0 ? cr : q == 1 ? -sr : q == 2 ? -cr : sr);
}
// -sin(2*pi*k/n)
constexpr float ctw_ns(int k, int n) {
    const int kk = ((k % n) + n) % n;
    const int q = (4 * kk) / n;
    const int num = 4 * kk - q * n;
    const double r = (2.0 * kPId * num) / (4.0 * n);
    const double cr = tp_cos(r), sr = tp_sin(r);
    const double s = (q == 0 ? sr : q == 1 ? cr : q == 2 ? -sr : -cr);
    return (float)(-s);
}

// ---------- named-scalar Z state: names 0..11 map to bins BSTART-1 .. BSTART+10 ----------
#define DECLZ \
    float zxr0=0.f,zxi0=0.f,zyr0=0.f,zyi0=0.f,  zxr1=0.f,zxi1=0.f,zyr1=0.f,zyi1=0.f, \
          zxr2=0.f,zxi2=0.f,zyr2=0.f,zyi2=0.f,  zxr3=0.f,zxi3=0.f,zyr3=0.f,zyi3=0.f, \
          zxr4=0.f,zxi4=0.f,zyr4=0.f,zyi4=0.f,  zxr5=0.f,zxi5=0.f,zyr5=0.f,zyi5=0.f, \
          zxr6=0.f,zxi6=0.f,zyr6=0.f,zyi6=0.f,  zxr7=0.f,zxi7=0.f,zyr7=0.f,zyi7=0.f, \
          zxr8=0.f,zxi8=0.f,zyr8=0.f,zyi8=0.f,  zxr9=0.f,zxi9=0.f,zyr9=0.f,zyi9=0.f, \
          zxr10=0.f,zxi10=0.f,zyr10=0.f,zyi10=0.f, zxr11=0.f,zxi11=0.f,zyr11=0.f,zyi11=0.f; \
    (void)zxr0;(void)zxi0;(void)zyr0;(void)zyi0;(void)zxr11;(void)zxi11;(void)zyr11;(void)zyi11;

// one bin update at (state name n, sample m): Z += d * omega^{b(m+TAU*H)}
#define UPDB(n, m) \
    if constexpr ((n) >= 1 && (n) <= NB) { \
        constexpr int   k_ = (BSTART + (n) - 1) * ((m) + TAU * HH); \
        constexpr float c_ = ctw_c(k_, NN); \
        constexpr float s_ = ctw_ns(k_, NN); \
        zxr##n = fmaf(dx, c_, zxr##n);  zxi##n = fmaf(dx, s_, zxi##n); \
        zyr##n = fmaf(dy, c_, zyr##n);  zyi##n = fmaf(dy, s_, zyi##n); \
    }

#define ALLB(m) UPDB(1,m) UPDB(2,m) UPDB(3,m) UPDB(4,m) UPDB(5,m) \
                UPDB(6,m) UPDB(7,m) UPDB(8,m) UPDB(9,m) UPDB(10,m)

// main-loop slot sample step: delta = new - old
#define UPD_M(m) \
    if constexpr ((m) < HH) { \
        const float dx = px[off + TAU*HH + NN + (m)] - px[off + TAU*HH + (m)]; \
        const float dy = py[off + TAU*HH + NN + (m)] - py[off + TAU*HH + (m)]; \
        ALLB(m) \
    }
// warmup slot sample step: add-only (builds X_{t0} exactly)
#define WRM_M(m) \
    if constexpr ((m) < HH) { \
        const float dx = px[TAU*HH + (m)]; \
        const float dy = py[TAU*HH + (m)]; \
        ALLB(m) \
    }

#define FORM(M) M(0) M(1) M(2) M(3) M(4) M(5) M(6) M(7) \
                M(8) M(9) M(10) M(11) M(12) M(13) M(14) M(15)

// emit one bin (state name nc, neighbors nm/np). PH = frame phase (rho & 3).
// X = i^{b*rho} Z ; W[b] = 0.5 X[b] - 0.25(X[b-1]+X[b+1]); |W| phase-factored.
#define EMTB(nm, nc, np) \
    if constexpr (((nc) - 1) >= EJ0 && ((nc) - 1) < EJ0 + EN) { \
        constexpr int BG = BSTART + (nc) - 1; \
        float wxr, wxi, wyr, wyi; \
        if constexpr (BG == 0) { \
            const float sx_ = (PH==0) ? zxr##np : (PH==1) ? -zxi##np : (PH==2) ? -zxr##np : zxi##np; \
            const float sy_ = (PH==0) ? zyr##np : (PH==1) ? -zyi##np : (PH==2) ? -zyr##np : zyi##np; \
            wxr = 0.5f*zxr##nc - 0.5f*sx_;  wxi = 0.5f*zxi##nc; \
            wyr = 0.5f*zyr##nc - 0.5f*sy_;  wyi = 0.5f*zyi##nc; \
        } else if constexpr (BG == NN/2) { \
            const float sx_ = (PH==0) ? zxr##nm : (PH==1) ? zxi##nm : (PH==2) ? -zxr##nm : -zxi##nm; \
            const float sy_ = (PH==0) ? zyr##nm : (PH==1) ? zyi##nm : (PH==2) ? -zyr##nm : -zyi##nm; \
            wxr = 0.5f*zxr##nc - 0.5f*sx_;  wxi = 0.5f*zxi##nc; \
            wyr = 0.5f*zyr##nc - 0.5f*sy_;  wyi = 0.5f*zyi##nc; \
        } else { \
            const float txr = (PH==0) ? (zxr##nm + zxr##np) : (PH==1) ? (zxi##nm - zxi##np) \
                            : (PH==2) ? (-zxr##nm - zxr##np) : (zxi##np - zxi##nm); \
            const float txi = (PH==0) ? (zxi##nm + zxi##np) : (PH==1) ? (zxr##np - zxr##nm) \
                            : (PH==2) ? (-zxi##nm - zxi##np) : (zxr##nm - zxr##np); \
            const float tyr = (PH==0) ? (zyr##nm + zyr##np) : (PH==1) ? (zyi##nm - zyi##np) \
                            : (PH==2) ? (-zyr##nm - zyr##np) : (zyi##np - zyi##nm); \
            const float tyi = (PH==0) ? (zyi##nm + zyi##np) : (PH==1) ? (zyr##np - zyr##nm) \
                            : (PH==2) ? (-zyi##nm - zyi##np) : (zyr##nm - zyr##np); \
            wxr = fmaf(-0.25f, txr, 0.5f*zxr##nc);  wxi = fmaf(-0.25f, txi, 0.5f*zxi##nc); \
            wyr = fmaf(-0.25f, tyr, 0.5f*zyr##nc);  wyi = fmaf(-0.25f, tyi, 0.5f*zyi##nc); \
        } \
        const float pxm = fmaf(wxr, wxr, wxi*wxi); \
        const float pym = fmaf(wyr, wyr, wyi*wyi); \
        const float sm_ = pxm + pym; \
        const float rt_ = sqrtf(pxm * pym); \
        sd2 += fmaf(-2.0f, rt_, sm_); \
        sy2 += pym; \
        slg = fmaf(0.5f, fabsf(__logf(__fdividef(pxm + 1e-14f, pym + 1e-14f))), slg); \
    }

#define FOREMT(M) M(0,1,2) M(1,2,3) M(2,3,4) M(3,4,5) M(4,5,6) \
                  M(5,6,7) M(6,7,8) M(7,8,9) M(8,9,10) M(9,10,11)

#define SLOT(t) { constexpr int TAU = (t); constexpr int PH = (t); FOREMT(EMTB) FORM(UPD_M) }
#define WARM(t) { constexpr int TAU = (t); FORM(WRM_M) }

// one (bin-group, frame-segment) worker. State bins BSTART..BSTART+NB-1,
// emit bins BSTART+EJ0 .. +EJ0+EN-1. OFF = staged j of frame 0, k=0.
template <int NN, int BSTART, int NB, int EJ0, int EN, int OFF>
__device__ __forceinline__ void run_group(const float* __restrict__ px_,
                                          const float* __restrict__ py_,
                                          int seg, float& sd2, float& sy2, float& slg)
{
    constexpr int HH = NN / 4;
    constexpr int FF = 4096 / NN + 1;           // frames
    const int t0 = (seg * FF) >> 3;
    const int t1 = ((seg + 1) * FF) >> 3;
    const int L  = t1 - t0;                      // frames this segment emits
    const float* __restrict__ px = px_ + OFF + t0 * HH;
    const float* __restrict__ py = py_ + OFF + t0 * HH;

    DECLZ
    WARM(0) WARM(1) WARM(2) WARM(3)             // Z = X_{t0} exactly

    int off = 0;
    const int nq = L >> 2, rem = L & 3;         // uniform nq within wave by seg design
#pragma unroll 1
    for (int q = 0; q < nq; ++q) {
        SLOT(0) SLOT(1) SLOT(2) SLOT(3)
        off += 4 * HH;
    }
    if (rem > 0) { SLOT(0) }
    if (rem > 1) { SLOT(1) }
    if (rem > 2) { SLOT(2) }
}

__global__ __launch_bounds__(1024)
void fused_sdft_kernel(const float* __restrict__ xg, const float* __restrict__ yg,
                       float* __restrict__ acc)
{
    constexpr int RS = 1106;                    // row stride (floats): 18 mod 32 -> spread banks
    __shared__ float ldsx[16][RS];
    __shared__ float ldsy[16][RS];
    __shared__ float red[16][3];

    const int tid  = threadIdx.x;
    const int row0 = blockIdx.x << 4;

    // ---- stage central 1024 samples/row/signal as float4 (j = 32 + i)
#pragma unroll 1
    for (int task = tid; task < 8192; task += 1024) {
        const int q = task & 255, rr = (task >> 8) & 15, sig = task >> 12;
        const float* __restrict__ src = sig ? yg : xg;
        const float4 v = reinterpret_cast<const float4*>(src)[((row0 + rr) << 8) + q];
        float* dst = sig ? &ldsy[rr][32 + (q << 2)] : &ldsx[rr][32 + (q << 2)];
        dst[0] = __expf(fmaf(v.x, kSigma, kMu));
        dst[1] = __expf(fmaf(v.y, kSigma, kMu));
        dst[2] = __expf(fmaf(v.z, kSigma, kMu));
        dst[3] = __expf(fmaf(v.w, kSigma, kMu));
    }
    // ---- reflect pads (32 each side) + zero tail [1088,1104) (discarded-update fuel)
#pragma unroll 1
    for (int task = tid; task < 2560; task += 1024) {
        const int p = task % 80, rem_ = task / 80;
        const int rr = rem_ & 15, sig = rem_ >> 4;
        const int j = (p < 32) ? p : (1024 + p);
        float v = 0.f;
        if (j < 1088) {
            const int i = (j < 32) ? (32 - j) : (2078 - j);
            const float* __restrict__ src = sig ? yg : xg;
            v = __expf(fmaf(src[((row0 + rr) << 10) + i], kSigma, kMu));
        }
        (sig ? ldsy[rr] : ldsx[rr])[j] = v;
    }
    __syncthreads();

    // ---- wave-pure schedule: wave pair (wid>>1) = group type; lanes = 16 rows x 4 segs
    const int wid = tid >> 6, lane = tid & 63;
    const int seg = ((wid & 1) << 2) + (lane >> 4);   // 0..7
    const int row = lane & 15;
    const float* lx = &ldsx[row][0];
    const float* ly = &ldsy[row][0];

    float sd2 = 0.f, sy2 = 0.f, slg = 0.f;
    switch (wid >> 1) {
        case 0:  run_group<64,  0,  9, 0, 8,  0>(lx, ly, seg, sd2, sy2, slg); break; // n64 bins 0-7
        case 1:  run_group<64,  7, 10, 1, 8,  0>(lx, ly, seg, sd2, sy2, slg); break; // n64 bins 8-15
        case 2:  run_group<64, 15, 10, 1, 8,  0>(lx, ly, seg, sd2, sy2, slg); break; // n64 bins 16-23
        case 3:  run_group<64, 23, 10, 1, 9,  0>(lx, ly, seg, sd2, sy2, slg); break; // n64 bins 24-32
        case 4:  run_group<32,  0,  9, 0, 8, 16>(lx, ly, seg, sd2, sy2, slg); break; // n32 bins 0-7
        case 5:  run_group<32,  7, 10, 1, 9, 16>(lx, ly, seg, sd2, sy2, slg); break; // n32 bins 8-16
        case 6:  run_group<16,  0,  9, 0, 9, 24>(lx, ly, seg, sd2, sy2, slg); break; // n16 bins 0-8
        default: run_group< 8,  0,  5, 0, 5, 28>(lx, ly, seg, sd2, sy2, slg); break; // n8  bins 0-4
    }

    // ---- reduce: wave shuffle -> LDS -> atomics (12 global accumulators)
#pragma unroll
    for (int o = 32; o > 0; o >>= 1) {
        sd2 += __shfl_down(sd2, o);
        sy2 += __shfl_down(sy2, o);
        slg += __shfl_down(slg, o);
    }
    if (lane == 0) { red[wid][0] = sd2; red[wid][1] = sy2; red[wid][2] = slg; }
    __syncthreads();
    if (tid < 16) {
        const int w2 = tid >> 1;
        const int res = (w2 < 4) ? 3 : (w2 < 6) ? 2 : (w2 == 6) ? 1 : 0; // n8=0,n16=1,n32=2,n64=3
        atomicAdd(&acc[(res * 3 + 0) * 64], red[tid][0]);
        atomicAdd(&acc[(res * 3 + 1) * 64], red[tid][1]);
        atomicAdd(&acc[(res * 3 + 2) * 64], red[tid][2]);
    }
}

__global__ void finalize_kernel(const float* __restrict__ acc, float* __restrict__ out)
{
    if (threadIdx.x == 0 && blockIdx.x == 0) {
        const float nel[4] = {10506240.f, 9474048.f, 8982528.f, 8785920.f};
        float sc = 0.f, mg = 0.f;
#pragma unroll
        for (int r = 0; r < 4; ++r) {
            const float a0 = acc[(r * 3 + 0) * 64];
            const float a1 = acc[(r * 3 + 1) * 64];
            const float a2 = acc[(r * 3 + 2) * 64];
            sc += sqrtf(a0) / (sqrtf(a1) + 1e-8f);
            mg += a2 / nel[r];
        }
        out[0] = sc * 0.25f;
        out[1] = mg * 0.25f;
    }
}

extern "C" void kernel_launch(void* const* d_in, const int* in_sizes, int n_in,
                              void* d_out, int out_size, void* d_ws, size_t ws_size,
                              hipStream_t stream)
{
    const float* x = (const float*)d_in[0];
    const float* y = (const float*)d_in[1];
    float* out = (float*)d_out;
    float* acc = (float*)d_ws;

    hipMemsetAsync(acc, 0, 12 * 64 * sizeof(float), stream);
    fused_sdft_kernel<<<256, 1024, 0, stream>>>(x, y, acc);
    finalize_kernel<<<1, 64, 0, stream>>>(acc, out);
}

// Round 5
// 141.506 us; speedup vs baseline: 2.6931x; 1.0001x over previous
//
#include <hip/hip_runtime.h>
#include <math.h>

static constexpr float kSigma = 3.5412f;
static constexpr float kMu    = -9.1232f;

// ---------- compile-time twiddles: cos / -sin of 2*pi*k/n (constexpr Taylor) ----------
constexpr double kPId = 3.14159265358979323846264338327950288;

constexpr double tp_sin(double r) {
    const double r2 = r * r;
    double t = r, s = r;
    t *= -r2 / (2.0 * 3.0);   s += t;
    t *= -r2 / (4.0 * 5.0);   s += t;
    t *= -r2 / (6.0 * 7.0);   s += t;
    t *= -r2 / (8.0 * 9.0);   s += t;
    t *= -r2 / (10.0 * 11.0); s += t;
    t *= -r2 / (12.0 * 13.0); s += t;
    return s;
}
constexpr double tp_cos(double r) {
    const double r2 = r * r;
    double t = 1.0, c = 1.0;
    t *= -r2 / (1.0 * 2.0);   c += t;
    t *= -r2 / (3.0 * 4.0);   c += t;
    t *= -r2 / (5.0 * 6.0);   c += t;
    t *= -r2 / (7.0 * 8.0);   c += t;
    t *= -r2 / (9.0 * 10.0);  c += t;
    t *= -r2 / (11.0 * 12.0); c += t;
    return c;
}
// cos(2*pi*k/n) via exact integer quadrant reduction
constexpr float ctw_c(int k, int n) {
    const int kk = ((k % n) + n) % n;
    const int q = (4 * kk) / n;
    const int num = 4 * kk - q * n;
    const double r = (2.0 * kPId * num) / (4.0 * n);
    const double cr = tp_cos(r), sr = tp_sin(r);
    return (float)(q == 0 ? cr : q == 1 ? -sr : q == 2 ? -cr : sr);
}
// -sin(2*pi*k/n)
constexpr float ctw_ns(int k, int n) {
    const int kk = ((k % n) + n) % n;
    const int q = (4 * kk) / n;
    const int num = 4 * kk - q * n;
    const double r = (2.0 * kPId * num) / (4.0 * n);
    const double cr = tp_cos(r), sr = tp_sin(r);
    const double s = (q == 0 ? sr : q == 1 ? cr : q == 2 ? -sr : -cr);
    return (float)(-s);
}

// ---------- named-scalar Z state: names 0..11 map to bins BSTART-1 .. BSTART+10 ----------
#define DECLZ \
    float zxr0=0.f,zxi0=0.f,zyr0=0.f,zyi0=0.f,  zxr1=0.f,zxi1=0.f,zyr1=0.f,zyi1=0.f, \
          zxr2=0.f,zxi2=0.f,zyr2=0.f,zyi2=0.f,  zxr3=0.f,zxi3=0.f,zyr3=0.f,zyi3=0.f, \
          zxr4=0.f,zxi4=0.f,zyr4=0.f,zyi4=0.f,  zxr5=0.f,zxi5=0.f,zyr5=0.f,zyi5=0.f, \
          zxr6=0.f,zxi6=0.f,zyr6=0.f,zyi6=0.f,  zxr7=0.f,zxi7=0.f,zyr7=0.f,zyi7=0.f, \
          zxr8=0.f,zxi8=0.f,zyr8=0.f,zyi8=0.f,  zxr9=0.f,zxi9=0.f,zyr9=0.f,zyi9=0.f, \
          zxr10=0.f,zxi10=0.f,zyr10=0.f,zyi10=0.f, zxr11=0.f,zxi11=0.f,zyr11=0.f,zyi11=0.f; \
    (void)zxr0;(void)zxi0;(void)zyr0;(void)zyi0;(void)zxr11;(void)zxi11;(void)zyr11;(void)zyi11;

// one bin update at (state name n, sample m): Z += d * omega^{b(m+TAU*H)}
#define UPDB(n, m) \
    if constexpr ((n) >= 1 && (n) <= NB) { \
        constexpr int   k_ = (BSTART + (n) - 1) * ((m) + TAU * HH); \
        constexpr float c_ = ctw_c(k_, NN); \
        constexpr float s_ = ctw_ns(k_, NN); \
        zxr##n = fmaf(dx, c_, zxr##n);  zxi##n = fmaf(dx, s_, zxi##n); \
        zyr##n = fmaf(dy, c_, zyr##n);  zyi##n = fmaf(dy, s_, zyi##n); \
    }

#define ALLB(m) UPDB(1,m) UPDB(2,m) UPDB(3,m) UPDB(4,m) UPDB(5,m) \
                UPDB(6,m) UPDB(7,m) UPDB(8,m) UPDB(9,m) UPDB(10,m)

// main-loop slot sample step: delta = new - old
#define UPD_M(m) \
    if constexpr ((m) < HH) { \
        const float dx = px[off + TAU*HH + NN + (m)] - px[off + TAU*HH + (m)]; \
        const float dy = py[off + TAU*HH + NN + (m)] - py[off + TAU*HH + (m)]; \
        ALLB(m) \
    }
// warmup slot sample step: add-only (builds X_{t0} exactly)
#define WRM_M(m) \
    if constexpr ((m) < HH) { \
        const float dx = px[TAU*HH + (m)]; \
        const float dy = py[TAU*HH + (m)]; \
        ALLB(m) \
    }

#define FORM(M) M(0) M(1) M(2) M(3) M(4) M(5) M(6) M(7) \
                M(8) M(9) M(10) M(11) M(12) M(13) M(14) M(15)

// emit one bin (state name nc, neighbors nm/np). PH = frame phase (rho & 3).
// X = i^{b*rho} Z ; W[b] = 0.5 X[b] - 0.25(X[b-1]+X[b+1]); |W| phase-factored.
#define EMTB(nm, nc, np) \
    if constexpr (((nc) - 1) >= EJ0 && ((nc) - 1) < EJ0 + EN) { \
        constexpr int BG = BSTART + (nc) - 1; \
        float wxr, wxi, wyr, wyi; \
        if constexpr (BG == 0) { \
            const float sx_ = (PH==0) ? zxr##np : (PH==1) ? -zxi##np : (PH==2) ? -zxr##np : zxi##np; \
            const float sy_ = (PH==0) ? zyr##np : (PH==1) ? -zyi##np : (PH==2) ? -zyr##np : zyi##np; \
            wxr = 0.5f*zxr##nc - 0.5f*sx_;  wxi = 0.5f*zxi##nc; \
            wyr = 0.5f*zyr##nc - 0.5f*sy_;  wyi = 0.5f*zyi##nc; \
        } else if constexpr (BG == NN/2) { \
            const float sx_ = (PH==0) ? zxr##nm : (PH==1) ? zxi##nm : (PH==2) ? -zxr##nm : -zxi##nm; \
            const float sy_ = (PH==0) ? zyr##nm : (PH==1) ? zyi##nm : (PH==2) ? -zyr##nm : -zyi##nm; \
            wxr = 0.5f*zxr##nc - 0.5f*sx_;  wxi = 0.5f*zxi##nc; \
            wyr = 0.5f*zyr##nc - 0.5f*sy_;  wyi = 0.5f*zyi##nc; \
        } else { \
            const float txr = (PH==0) ? (zxr##nm + zxr##np) : (PH==1) ? (zxi##nm - zxi##np) \
                            : (PH==2) ? (-zxr##nm - zxr##np) : (zxi##np - zxi##nm); \
            const float txi = (PH==0) ? (zxi##nm + zxi##np) : (PH==1) ? (zxr##np - zxr##nm) \
                            : (PH==2) ? (-zxi##nm - zxi##np) : (zxr##nm - zxr##np); \
            const float tyr = (PH==0) ? (zyr##nm + zyr##np) : (PH==1) ? (zyi##nm - zyi##np) \
                            : (PH==2) ? (-zyr##nm - zyr##np) : (zyi##np - zyi##nm); \
            const float tyi = (PH==0) ? (zyi##nm + zyi##np) : (PH==1) ? (zyr##np - zyr##nm) \
                            : (PH==2) ? (-zyi##nm - zyi##np) : (zyr##nm - zyr##np); \
            wxr = fmaf(-0.25f, txr, 0.5f*zxr##nc);  wxi = fmaf(-0.25f, txi, 0.5f*zxi##nc); \
            wyr = fmaf(-0.25f, tyr, 0.5f*zyr##nc);  wyi = fmaf(-0.25f, tyi, 0.5f*zyi##nc); \
        } \
        const float pxm = fmaf(wxr, wxr, wxi*wxi); \
        const float pym = fmaf(wyr, wyr, wyi*wyi); \
        const float sm_ = pxm + pym; \
        const float rt_ = sqrtf(pxm * pym); \
        sd2 += fmaf(-2.0f, rt_, sm_); \
        sy2 += pym; \
        slg = fmaf(0.5f, fabsf(__logf(__fdividef(pxm + 1e-14f, pym + 1e-14f))), slg); \
    }

#define FOREMT(M) M(0,1,2) M(1,2,3) M(2,3,4) M(3,4,5) M(4,5,6) \
                  M(5,6,7) M(6,7,8) M(7,8,9) M(8,9,10) M(9,10,11)

#define SLOT(t) { constexpr int TAU = (t); constexpr int PH = (t); FOREMT(EMTB) FORM(UPD_M) }
#define WARM(t) { constexpr int TAU = (t); FORM(WRM_M) }

// one (bin-group, frame-segment) worker. State bins BSTART..BSTART+NB-1,
// emit bins BSTART+EJ0 .. +EJ0+EN-1. OFF = staged j of frame 0, k=0.
template <int NN, int BSTART, int NB, int EJ0, int EN, int OFF>
__device__ __forceinline__ void run_group(const float* __restrict__ px_,
                                          const float* __restrict__ py_,
                                          int seg, float& sd2, float& sy2, float& slg)
{
    constexpr int HH = NN / 4;
    constexpr int FF = 4096 / NN + 1;           // frames
    const int t0 = (seg * FF) >> 3;
    const int t1 = ((seg + 1) * FF) >> 3;
    const int L  = t1 - t0;                      // frames this segment emits
    const float* __restrict__ px = px_ + OFF + t0 * HH;
    const float* __restrict__ py = py_ + OFF + t0 * HH;

    DECLZ
    WARM(0) WARM(1) WARM(2) WARM(3)             // Z = X_{t0} exactly

    int off = 0;
    const int nq = L >> 2, rem = L & 3;         // uniform nq within wave by seg design
#pragma unroll 1
    for (int q = 0; q < nq; ++q) {
        SLOT(0) SLOT(1) SLOT(2) SLOT(3)
        off += 4 * HH;
    }
    if (rem > 0) { SLOT(0) }
    if (rem > 1) { SLOT(1) }
    if (rem > 2) { SLOT(2) }
}

__global__ __launch_bounds__(1024, 4)   // 4 waves/EU floor -> VGPR cap 128 (was 64: spilled)
void fused_sdft_kernel(const float* __restrict__ xg, const float* __restrict__ yg,
                       float* __restrict__ acc)
{
    constexpr int RS = 1106;                    // row stride (floats): 18 mod 32 -> spread banks
    __shared__ float ldsx[16][RS];
    __shared__ float ldsy[16][RS];
    __shared__ float red[16][3];

    const int tid  = threadIdx.x;
    const int row0 = blockIdx.x << 4;

    // ---- stage central 1024 samples/row/signal as float4 (j = 32 + i)
#pragma unroll 1
    for (int task = tid; task < 8192; task += 1024) {
        const int q = task & 255, rr = (task >> 8) & 15, sig = task >> 12;
        const float* __restrict__ src = sig ? yg : xg;
        const float4 v = reinterpret_cast<const float4*>(src)[((row0 + rr) << 8) + q];
        float* dst = sig ? &ldsy[rr][32 + (q << 2)] : &ldsx[rr][32 + (q << 2)];
        dst[0] = __expf(fmaf(v.x, kSigma, kMu));
        dst[1] = __expf(fmaf(v.y, kSigma, kMu));
        dst[2] = __expf(fmaf(v.z, kSigma, kMu));
        dst[3] = __expf(fmaf(v.w, kSigma, kMu));
    }
    // ---- reflect pads (32 each side) + zero tail [1088,1104) (discarded-update fuel)
#pragma unroll 1
    for (int task = tid; task < 2560; task += 1024) {
        const int p = task % 80, rem_ = task / 80;
        const int rr = rem_ & 15, sig = rem_ >> 4;
        const int j = (p < 32) ? p : (1024 + p);
        float v = 0.f;
        if (j < 1088) {
            const int i = (j < 32) ? (32 - j) : (2078 - j);
            const float* __restrict__ src = sig ? yg : xg;
            v = __expf(fmaf(src[((row0 + rr) << 10) + i], kSigma, kMu));
        }
        (sig ? ldsy[rr] : ldsx[rr])[j] = v;
    }
    __syncthreads();

    // ---- wave-pure schedule: wave pair (wid>>1) = group type; lanes = 16 rows x 4 segs
    const int wid = tid >> 6, lane = tid & 63;
    const int seg = ((wid & 1) << 2) + (lane >> 4);   // 0..7
    const int row = lane & 15;
    const float* lx = &ldsx[row][0];
    const float* ly = &ldsy[row][0];

    float sd2 = 0.f, sy2 = 0.f, slg = 0.f;
    switch (wid >> 1) {
        case 0:  run_group<64,  0,  9, 0, 8,  0>(lx, ly, seg, sd2, sy2, slg); break; // n64 bins 0-7
        case 1:  run_group<64,  7, 10, 1, 8,  0>(lx, ly, seg, sd2, sy2, slg); break; // n64 bins 8-15
        case 2:  run_group<64, 15, 10, 1, 8,  0>(lx, ly, seg, sd2, sy2, slg); break; // n64 bins 16-23
        case 3:  run_group<64, 23, 10, 1, 9,  0>(lx, ly, seg, sd2, sy2, slg); break; // n64 bins 24-32
        case 4:  run_group<32,  0,  9, 0, 8, 16>(lx, ly, seg, sd2, sy2, slg); break; // n32 bins 0-7
        case 5:  run_group<32,  7, 10, 1, 9, 16>(lx, ly, seg, sd2, sy2, slg); break; // n32 bins 8-16
        case 6:  run_group<16,  0,  9, 0, 9, 24>(lx, ly, seg, sd2, sy2, slg); break; // n16 bins 0-8
        default: run_group< 8,  0,  5, 0, 5, 28>(lx, ly, seg, sd2, sy2, slg); break; // n8  bins 0-4
    }

    // ---- reduce: wave shuffle -> LDS -> atomics (12 global accumulators)
#pragma unroll
    for (int o = 32; o > 0; o >>= 1) {
        sd2 += __shfl_down(sd2, o);
        sy2 += __shfl_down(sy2, o);
        slg += __shfl_down(slg, o);
    }
    if (lane == 0) { red[wid][0] = sd2; red[wid][1] = sy2; red[wid][2] = slg; }
    __syncthreads();
    if (tid < 16) {
        const int w2 = tid >> 1;
        const int res = (w2 < 4) ? 3 : (w2 < 6) ? 2 : (w2 == 6) ? 1 : 0; // n8=0,n16=1,n32=2,n64=3
        atomicAdd(&acc[(res * 3 + 0) * 64], red[tid][0]);
        atomicAdd(&acc[(res * 3 + 1) * 64], red[tid][1]);
        atomicAdd(&acc[(res * 3 + 2) * 64], red[tid][2]);
    }
}

__global__ void finalize_kernel(const float* __restrict__ acc, float* __restrict__ out)
{
    if (threadIdx.x == 0 && blockIdx.x == 0) {
        const float nel[4] = {10506240.f, 9474048.f, 8982528.f, 8785920.f};
        float sc = 0.f, mg = 0.f;
#pragma unroll
        for (int r = 0; r < 4; ++r) {
            const float a0 = acc[(r * 3 + 0) * 64];
            const float a1 = acc[(r * 3 + 1) * 64];
            const float a2 = acc[(r * 3 + 2) * 64];
            sc += sqrtf(a0) / (sqrtf(a1) + 1e-8f);
            mg += a2 / nel[r];
        }
        out[0] = sc * 0.25f;
        out[1] = mg * 0.25f;
    }
}

extern "C" void kernel_launch(void* const* d_in, const int* in_sizes, int n_in,
                              void* d_out, int out_size, void* d_ws, size_t ws_size,
                              hipStream_t stream)
{
    const float* x = (const float*)d_in[0];
    const float* y = (const float*)d_in[1];
    float* out = (float*)d_out;
    float* acc = (float*)d_ws;

    hipMemsetAsync(acc, 0, 12 * 64 * sizeof(float), stream);
    fused_sdft_kernel<<<256, 1024, 0, stream>>>(x, y, acc);
    finalize_kernel<<<1, 64, 0, stream>>>(acc, out);
}